// Round 1
// 664.728 us; speedup vs baseline: 1.0044x; 1.0044x over previous
//
#include <hip/hip_runtime.h>
#include <math.h>

// Problem constants (fixed by the reference setup)
constexpr int B = 32;
constexpr int L = 4096;
constexpr int D = 1024;
constexpr float NEG_INF = -1e30f;

// One-pass online-softmax partials: CH waves per batch row, each wave owns
// L/CH consecutive sequence positions and all of D (16 floats per lane).
constexpr int CH  = 128;       // chunks (waves) per b -> grid 1024 blocks = exactly 4/CU
constexpr int RPW = L / CH;    // 32 rows per wave

using f32x4 = __attribute__((ext_vector_type(4))) float;

// Workspace layout (floats):
//   scores : B*L = 131072 | pm,pl : B*CH each | (pad, was Mden) | pacc : B*CH*D (16 MB)
constexpr size_t WS_SCORES = 0;
constexpr size_t WS_PM     = WS_SCORES + (size_t)B * L;
constexpr size_t WS_PL     = WS_PM + (size_t)B * CH;
constexpr size_t WS_PAD    = WS_PL + (size_t)B * CH;
constexpr size_t WS_PACC   = WS_PAD + 2 * B;   // 16B-aligned

// 2-row ILP: ~95 live VGPRs -> fits the 128-VGPR budget of 4 waves/SIMD with
// no spills (4-row staging in R2 blew past 128 and was neutral). Non-temporal
// seq loads: stream-once data, keep L2 for pacc.
// R3: merged per-pair rescale — m' = max3(m, sc0, sc1), ONE uniform branch per
// 2 rows instead of two; shorter serial chain, identical online-softmax math
// (masked-chunk self-healing at combine preserved: e = exp(-1e30 - M) = 0).
__global__ __launch_bounds__(256, 4) void pass1_kernel(
    const float* __restrict__ seq, const float* __restrict__ vec,
    const int* __restrict__ mask, float* __restrict__ scores,
    float* __restrict__ pm, float* __restrict__ pl, float* __restrict__ pacc)
{
    const int wave = blockIdx.x * 4 + (threadIdx.x >> 6);  // [0, B*CH)
    const int lane = threadIdx.x & 63;
    const int b = wave >> 7;          // wave / CH  (CH==128)
    const int c = wave & (CH - 1);
    const int l0 = c * RPW;

    // vector fragment: lane covers d = lane*4 + j*256, j=0..3
    const f32x4* v4 = (const f32x4*)(vec + (size_t)b * D);
    const f32x4 v0 = v4[lane], v1 = v4[lane + 64], v2 = v4[lane + 128], v3 = v4[lane + 192];

    float m = -INFINITY, lsum = 0.f;
    f32x4 a0 = {0,0,0,0}, a1 = {0,0,0,0}, a2 = {0,0,0,0}, a3 = {0,0,0,0};

    const f32x4* srow = (const f32x4*)(seq + ((size_t)b * L + l0) * D);
    const int rowbase = b * L + l0;

    for (int it = 0; it < RPW / 2; ++it) {
        // uniform mask pair -> scalar load
        const int2 mk = *(const int2*)(mask + rowbase + it * 2);

        // burst-load 2 rows (8 dwordx4/lane, non-temporal) for MLP
        const f32x4* p0 = srow + (size_t)(it * 2) * (D / 4);
        const f32x4* p1 = p0 + (D / 4);
        f32x4 s00 = __builtin_nontemporal_load(p0 + lane);
        f32x4 s01 = __builtin_nontemporal_load(p0 + lane + 64);
        f32x4 s02 = __builtin_nontemporal_load(p0 + lane + 128);
        f32x4 s03 = __builtin_nontemporal_load(p0 + lane + 192);
        f32x4 s10 = __builtin_nontemporal_load(p1 + lane);
        f32x4 s11 = __builtin_nontemporal_load(p1 + lane + 64);
        f32x4 s12 = __builtin_nontemporal_load(p1 + lane + 128);
        f32x4 s13 = __builtin_nontemporal_load(p1 + lane + 192);

        // 2 independent partial dots
        f32x4 d0v = s00 * v0 + s01 * v1 + s02 * v2 + s03 * v3;
        f32x4 d1v = s10 * v0 + s11 * v1 + s12 * v2 + s13 * v3;
        float dot0 = d0v.x + d0v.y + d0v.z + d0v.w;
        float dot1 = d1v.x + d1v.y + d1v.z + d1v.w;

        // interleaved butterfly chains
        #pragma unroll
        for (int off = 32; off; off >>= 1) {
            dot0 += __shfl_xor(dot0, off, 64);
            dot1 += __shfl_xor(dot1, off, 64);
        }

        const float sc0 = (mk.x > 0) ? dot0 : NEG_INF;
        const float sc1 = (mk.y > 0) ? dot1 : NEG_INF;

        // single merged rescale (wave-uniform branch; rare: ~5/32 rows)
        const float mNew = fmaxf(fmaxf(sc0, sc1), m);   // -> v_max3_f32
        if (mNew > m) {
            const float scale = __expf(m - mNew);       // exp(-inf)=0 on first hit
            lsum *= scale;
            a0 *= scale; a1 *= scale; a2 *= scale; a3 *= scale;
            m = mNew;
        }
        const float p0w = __expf(sc0 - m);
        const float p1w = __expf(sc1 - m);
        lsum += p0w + p1w;
        a0 += p0w * s00; a1 += p0w * s01; a2 += p0w * s02; a3 += p0w * s03;
        a0 += p1w * s10; a1 += p1w * s11; a2 += p1w * s12; a3 += p1w * s13;

        if (lane == 0) *(float2*)(scores + rowbase + it * 2) = make_float2(sc0, sc1);
    }

    f32x4* aout = (f32x4*)(pacc + (size_t)wave * D);
    aout[lane] = a0; aout[lane + 64] = a1; aout[lane + 128] = a2; aout[lane + 192] = a3;
    if (lane == 0) { pm[wave] = m; pl[wave] = lsum; }
}

// grid (B, 8), 128 threads: block (b, y) reduces 128 chunk-partials over a
// 128-wide d-slice AND normalizes a 512-wide l-slice of the weights output.
// M/denom recomputed per block (cheap, identical values) — Mden buffer and
// the separate weights kernel are gone (one fewer launch + no global RT).
__global__ __launch_bounds__(128) void combine_kernel(
    const float* __restrict__ pm, const float* __restrict__ pl,
    const float* __restrict__ pacc, const float* __restrict__ scores,
    float* __restrict__ pooled, float* __restrict__ out_w)
{
    const int b  = blockIdx.x;
    const int y  = blockIdx.y;         // 0..7
    const int ds = y * 128;
    const int t  = threadIdx.x;        // 0..127

    __shared__ float red[128];
    __shared__ float wgt[128];

    const float mc = pm[b * CH + t];
    const float lc = pl[b * CH + t];

    red[t] = mc; __syncthreads();
    #pragma unroll
    for (int s = 64; s; s >>= 1) { if (t < s) red[t] = fmaxf(red[t], red[t + s]); __syncthreads(); }
    const float M = red[0];
    __syncthreads();

    const float e = __expf(mc - M);
    wgt[t] = e;
    red[t] = lc * e; __syncthreads();
    #pragma unroll
    for (int s = 64; s; s >>= 1) { if (t < s) red[t] += red[t + s]; __syncthreads(); }
    const float denom = red[0];
    const float inv = 1.f / denom;

    // pooled d-slice: deeper unroll -> more bytes in flight at 2 waves/block
    float acc = 0.f;
    const float* base = pacc + (size_t)b * CH * D + ds + t;
    #pragma unroll 16
    for (int c = 0; c < CH; ++c)
        acc += base[(size_t)c * D] * wgt[c];
    pooled[b * D + ds + t] = acc * inv;

    // weights l-slice: 512 scores per block, float4 per thread (scores stay L2-hot)
    const int l0 = y * 512;
    const f32x4 s4 = ((const f32x4*)(scores + (size_t)b * L + l0))[t];
    f32x4 w;
    w.x = __expf(s4.x - M) * inv;
    w.y = __expf(s4.y - M) * inv;
    w.z = __expf(s4.z - M) * inv;
    w.w = __expf(s4.w - M) * inv;
    ((f32x4*)(out_w + (size_t)b * L + l0))[t] = w;
}

extern "C" void kernel_launch(void* const* d_in, const int* in_sizes, int n_in,
                              void* d_out, int out_size, void* d_ws, size_t ws_size,
                              hipStream_t stream) {
    const float* seq  = (const float*)d_in[0];
    const float* vec  = (const float*)d_in[1];
    const int*   mask = (const int*)d_in[2];
    float* out = (float*)d_out;           // pooled [B*D] then weights [B*L]

    float* ws     = (float*)d_ws;
    float* scores = ws + WS_SCORES;
    float* pm     = ws + WS_PM;
    float* pl     = ws + WS_PL;
    float* pacc   = ws + WS_PACC;

    pass1_kernel<<<(B * CH) / 4, 256, 0, stream>>>(seq, vec, mask, scores, pm, pl, pacc);
    combine_kernel<<<dim3(B, D / 128), 128, 0, stream>>>(pm, pl, pacc, scores, out, out + B * D);
}

// Round 2
// 620.572 us; speedup vs baseline: 1.0759x; 1.0712x over previous
//
#include <hip/hip_runtime.h>
#include <math.h>

// Problem constants (fixed by the reference setup)
constexpr int B = 32;
constexpr int L = 4096;
constexpr int D = 1024;
constexpr float NEG_INF = -1e30f;

// One-pass online-softmax partials: CH waves per batch row, each wave owns
// L/CH consecutive sequence positions and all of D (16 floats per lane).
constexpr int CH  = 128;       // chunks (waves) per b -> grid 1024 blocks = exactly 4/CU
constexpr int RPW = L / CH;    // 32 rows per wave

using f32x4 = __attribute__((ext_vector_type(4))) float;

// Workspace layout (floats):
//   scores : B*L = 131072 | pm,pl : B*CH each | (pad) | pacc : B*CH*D (16 MB)
constexpr size_t WS_SCORES = 0;
constexpr size_t WS_PM     = WS_SCORES + (size_t)B * L;
constexpr size_t WS_PL     = WS_PM + (size_t)B * CH;
constexpr size_t WS_PAD    = WS_PL + (size_t)B * CH;
constexpr size_t WS_PACC   = WS_PAD + 2 * B;   // 16B-aligned

// R4: mask-skip. Masked rows (~50%) have weight == exactly 0 and score ==
// NEG_INF independent of the dot product -> never load their sequence data.
// Wave reads its 32 mask values once (ballot -> uniform bitmap), then walks
// set bits two rows at a time (keeps the 8-dwordx4-in-flight dual-row MLP).
// Halves pass1 HBM traffic: 529 MB -> ~273 MB.
__global__ __launch_bounds__(256, 4) void pass1_kernel(
    const float* __restrict__ seq, const float* __restrict__ vec,
    const int* __restrict__ mask, float* __restrict__ scores,
    float* __restrict__ pm, float* __restrict__ pl, float* __restrict__ pacc)
{
    const int wave = blockIdx.x * 4 + (threadIdx.x >> 6);  // [0, B*CH)
    const int lane = threadIdx.x & 63;
    const int b = wave >> 7;          // wave / CH  (CH==128)
    const int c = wave & (CH - 1);
    const int l0 = c * RPW;

    // vector fragment: lane covers d = lane*4 + j*256, j=0..3
    const f32x4* v4 = (const f32x4*)(vec + (size_t)b * D);
    const f32x4 v0 = v4[lane], v1 = v4[lane + 64], v2 = v4[lane + 128], v3 = v4[lane + 192];

    const int rowbase = b * L + l0;
    const f32x4* srow = (const f32x4*)(seq + (size_t)rowbase * D);

    // wave-uniform bitmap of unmasked rows (bit i == row l0+i live), i<32
    const int mv = mask[rowbase + (lane & 31)];
    unsigned long long bits = __ballot((lane < 32) && (mv > 0));

    float m = -INFINITY, lsum = 0.f;
    f32x4 a0 = {0,0,0,0}, a1 = {0,0,0,0}, a2 = {0,0,0,0}, a3 = {0,0,0,0};
    float myscore = NEG_INF;          // lane i holds score of row l0+i (i<32)

    while (bits) {
        const int r0 = __builtin_ctzll(bits); bits &= bits - 1;
        const f32x4* p0 = srow + (size_t)r0 * (D / 4);
        f32x4 s00 = __builtin_nontemporal_load(p0 + lane);
        f32x4 s01 = __builtin_nontemporal_load(p0 + lane + 64);
        f32x4 s02 = __builtin_nontemporal_load(p0 + lane + 128);
        f32x4 s03 = __builtin_nontemporal_load(p0 + lane + 192);

        if (bits) {
            // dual-row path (75% of pair draws): full MLP burst
            const int r1 = __builtin_ctzll(bits); bits &= bits - 1;
            const f32x4* p1 = srow + (size_t)r1 * (D / 4);
            f32x4 s10 = __builtin_nontemporal_load(p1 + lane);
            f32x4 s11 = __builtin_nontemporal_load(p1 + lane + 64);
            f32x4 s12 = __builtin_nontemporal_load(p1 + lane + 128);
            f32x4 s13 = __builtin_nontemporal_load(p1 + lane + 192);

            f32x4 d0v = s00 * v0 + s01 * v1 + s02 * v2 + s03 * v3;
            f32x4 d1v = s10 * v0 + s11 * v1 + s12 * v2 + s13 * v3;
            float dot0 = d0v.x + d0v.y + d0v.z + d0v.w;
            float dot1 = d1v.x + d1v.y + d1v.z + d1v.w;

            #pragma unroll
            for (int off = 32; off; off >>= 1) {
                dot0 += __shfl_xor(dot0, off, 64);
                dot1 += __shfl_xor(dot1, off, 64);
            }

            // merged rescale: one uniform branch per pair (rare taken)
            const float mNew = fmaxf(fmaxf(dot0, dot1), m);   // v_max3_f32
            if (mNew > m) {
                const float scale = __expf(m - mNew);         // exp(-inf)=0 first hit
                lsum *= scale;
                a0 *= scale; a1 *= scale; a2 *= scale; a3 *= scale;
                m = mNew;
            }
            const float p0w = __expf(dot0 - m);
            const float p1w = __expf(dot1 - m);
            lsum += p0w + p1w;
            a0 += p0w * s00; a1 += p0w * s01; a2 += p0w * s02; a3 += p0w * s03;
            a0 += p1w * s10; a1 += p1w * s11; a2 += p1w * s12; a3 += p1w * s13;

            if (lane == r0) myscore = dot0;
            if (lane == r1) myscore = dot1;
        } else {
            // single-row tail
            f32x4 d0v = s00 * v0 + s01 * v1 + s02 * v2 + s03 * v3;
            float dot0 = d0v.x + d0v.y + d0v.z + d0v.w;
            #pragma unroll
            for (int off = 32; off; off >>= 1)
                dot0 += __shfl_xor(dot0, off, 64);

            if (dot0 > m) {
                const float scale = __expf(m - dot0);
                lsum *= scale;
                a0 *= scale; a1 *= scale; a2 *= scale; a3 *= scale;
                m = dot0;
            }
            const float p = __expf(dot0 - m);
            lsum += p;
            a0 += p * s00; a1 += p * s01; a2 += p * s02; a3 += p * s03;

            if (lane == r0) myscore = dot0;
        }
    }

    // coalesced score write: lane i owns row i (masked rows stay NEG_INF)
    if (lane < 32) scores[rowbase + lane] = myscore;

    f32x4* aout = (f32x4*)(pacc + (size_t)wave * D);
    aout[lane] = a0; aout[lane + 64] = a1; aout[lane + 128] = a2; aout[lane + 192] = a3;
    if (lane == 0) { pm[wave] = m; pl[wave] = lsum; }
}

// grid (B, 8), 128 threads: block (b, y) reduces 128 chunk-partials over a
// 128-wide d-slice AND normalizes a 512-wide l-slice of the weights output.
// M/denom recomputed per block (cheap, identical values).
__global__ __launch_bounds__(128) void combine_kernel(
    const float* __restrict__ pm, const float* __restrict__ pl,
    const float* __restrict__ pacc, const float* __restrict__ scores,
    float* __restrict__ pooled, float* __restrict__ out_w)
{
    const int b  = blockIdx.x;
    const int y  = blockIdx.y;         // 0..7
    const int ds = y * 128;
    const int t  = threadIdx.x;        // 0..127

    __shared__ float red[128];
    __shared__ float wgt[128];

    const float mc = pm[b * CH + t];
    const float lc = pl[b * CH + t];

    red[t] = mc; __syncthreads();
    #pragma unroll
    for (int s = 64; s; s >>= 1) { if (t < s) red[t] = fmaxf(red[t], red[t + s]); __syncthreads(); }
    const float M = red[0];
    __syncthreads();

    const float e = __expf(mc - M);    // all-masked chunk: exp(-inf - M) = 0
    wgt[t] = e;
    red[t] = lc * e; __syncthreads();
    #pragma unroll
    for (int s = 64; s; s >>= 1) { if (t < s) red[t] += red[t + s]; __syncthreads(); }
    const float denom = red[0];
    const float inv = 1.f / denom;

    // pooled d-slice: deep unroll -> more bytes in flight at 2 waves/block
    float acc = 0.f;
    const float* base = pacc + (size_t)b * CH * D + ds + t;
    #pragma unroll 16
    for (int c = 0; c < CH; ++c)
        acc += base[(size_t)c * D] * wgt[c];
    pooled[b * D + ds + t] = acc * inv;

    // weights l-slice: 512 scores per block, float4 per thread (L2-hot)
    const int l0 = y * 512;
    const f32x4 s4 = ((const f32x4*)(scores + (size_t)b * L + l0))[t];
    f32x4 w;
    w.x = __expf(s4.x - M) * inv;
    w.y = __expf(s4.y - M) * inv;
    w.z = __expf(s4.z - M) * inv;
    w.w = __expf(s4.w - M) * inv;
    ((f32x4*)(out_w + (size_t)b * L + l0))[t] = w;
}

extern "C" void kernel_launch(void* const* d_in, const int* in_sizes, int n_in,
                              void* d_out, int out_size, void* d_ws, size_t ws_size,
                              hipStream_t stream) {
    const float* seq  = (const float*)d_in[0];
    const float* vec  = (const float*)d_in[1];
    const int*   mask = (const int*)d_in[2];
    float* out = (float*)d_out;           // pooled [B*D] then weights [B*L]

    float* ws     = (float*)d_ws;
    float* scores = ws + WS_SCORES;
    float* pm     = ws + WS_PM;
    float* pl     = ws + WS_PL;
    float* pacc   = ws + WS_PACC;

    pass1_kernel<<<(B * CH) / 4, 256, 0, stream>>>(seq, vec, mask, scores, pm, pl, pacc);
    combine_kernel<<<dim3(B, D / 128), 128, 0, stream>>>(pm, pl, pacc, scores, out, out + B * D);
}